// Round 1
// 934.863 us; speedup vs baseline: 1.1950x; 1.1950x over previous
//
#include <hip/hip_runtime.h>
#include <stdint.h>

#define T_TOKENS 8192
#define K_IN 4096
#define N_OUT 12288

#define BM 256
#define BN 256
#define BK 128
#define NT (K_IN / BK)                              // 32 K-tiles
#define GRID_X ((T_TOKENS / BM) * (N_OUT / BN))     // 32*48 = 1536
#define CPX (GRID_X / 8)                            // 192 blocks per XCD

using int32x4 = __attribute__((ext_vector_type(4))) int;

#define BAR() do { asm volatile("" ::: "memory"); __builtin_amdgcn_s_barrier(); } while (0)
#define LGKM0() asm volatile("s_waitcnt lgkmcnt(0)" ::: "memory")

// ---------------- Kernel 1: per-token symmetric int8 quant ----------------
__global__ void quant_rows(const float* __restrict__ x,
                           int8_t* __restrict__ xq,
                           float* __restrict__ xs) {
    const int t = blockIdx.x;
    const int tid = threadIdx.x;
    const float* row = x + (size_t)t * K_IN;
    float4 v[4];
    float am = 0.0f;
#pragma unroll
    for (int i = 0; i < 4; ++i) {
        v[i] = ((const float4*)row)[tid + 256 * i];
        am = fmaxf(am, fmaxf(fmaxf(fabsf(v[i].x), fabsf(v[i].y)),
                             fmaxf(fabsf(v[i].z), fabsf(v[i].w))));
    }
#pragma unroll
    for (int off = 32; off > 0; off >>= 1)
        am = fmaxf(am, __shfl_xor(am, off));
    __shared__ float red[4];
    if ((tid & 63) == 0) red[tid >> 6] = am;
    __syncthreads();
    am = fmaxf(fmaxf(red[0], red[1]), fmaxf(red[2], red[3]));
    const float scale = fmaxf(am, 1e-8f) / 127.0f;  // matches reference x_scale
    if (tid == 0) xs[t] = scale;
    char4* dst = (char4*)(xq + (size_t)t * K_IN);
#pragma unroll
    for (int i = 0; i < 4; ++i) {
        float4 f = v[i];
        char4 c;
        float r;
        r = fminf(fmaxf(rintf(f.x / scale), -127.0f), 127.0f); c.x = (signed char)(int)r;
        r = fminf(fmaxf(rintf(f.y / scale), -127.0f), 127.0f); c.y = (signed char)(int)r;
        r = fminf(fmaxf(rintf(f.z / scale), -127.0f), 127.0f); c.z = (signed char)(int)r;
        r = fminf(fmaxf(rintf(f.w / scale), -127.0f), 127.0f); c.w = (signed char)(int)r;
        dst[tid + 256 * i] = c;
    }
}

// ---------------- Kernel 2: pack int32 weight -> int8 ----------------
__global__ void pack_weight(const int* __restrict__ w, int8_t* __restrict__ wq) {
    const int idx = blockIdx.x * 256 + threadIdx.x;
    int4 v = ((const int4*)w)[idx];
    char4 c;
    c.x = (signed char)v.x; c.y = (signed char)v.y;
    c.z = (signed char)v.z; c.w = (signed char)v.w;
    ((char4*)wq)[idx] = c;
}

// ---------------- Kernel 3: int8 GEMM, 256x256 8-phase pipelined ----------------
// C[m][n] = sum_k A[m][k]*W[n][k]; out = acc*xs[m]*wsc[n]+bias[n].
// BM=BN=256, BK=128 int8 (== bf16 template's 128B rows). 8 waves (2M x 4N),
// per-wave 128x64 output = 8x4 frags of mfma_i32_16x16x64_i8, 2 k-steps/K-tile.
// LDS 128 KiB: A[2][256][128] @0, B[2][256][128] @65536, double-buffered.
// Swizzle: 16B k-block kb stored at position kb ^ (row&7); applied on the
// pre-swizzled GLOBAL source (global_load_lds dest stays linear, rule #21).
// 4 phases/K-tile: {ds_read quadrant | stage 1 half-tile; bar; lgkmcnt(0);
// setprio(1); 16 MFMA; setprio(0); bar}. Stage slots: P0:B1(j+1) P1:A1(j+1)
// (idle buf), P2:B0(j+2) P3:A0(j+2) (current buf; B halves free after P1,
// A halves after P2). Boundary s_waitcnt vmcnt(4) once per K-tile keeps 2
// half-tiles in flight; never vmcnt(0) in the main loop.
template<int AR, int IL>
__device__ __forceinline__ void mfma_quad(int32x4 (&acc)[8][4],
                                          int32x4 (&a)[4][2],
                                          int32x4 (&b)[4][2]) {
#pragma unroll
    for (int im = 0; im < 4; ++im)
#pragma unroll
        for (int in = 0; in < 2; ++in)
#pragma unroll
            for (int kk = 0; kk < 2; ++kk)
                acc[AR + im][IL + in] = __builtin_amdgcn_mfma_i32_16x16x64_i8(
                    a[im][kk], b[IL + in][kk], acc[AR + im][IL + in], 0, 0, 0);
}

__global__ __launch_bounds__(512, 2) void gemm_i8(
        const int8_t* __restrict__ Aq, const int8_t* __restrict__ Bq,
        const float* __restrict__ xs, const float* __restrict__ wsc,
        const float* __restrict__ bias, float* __restrict__ out) {
    extern __shared__ int8_t sm[];  // 131072 B

    const int tid  = threadIdx.x;
    const int lane = tid & 63;
    const int wid  = tid >> 6;      // 0..7
    const int wm   = wid >> 2;      // 0..1
    const int wn   = wid & 3;       // 0..3
    const int fr   = lane & 15;     // fragment row (A: m, B: n)
    const int q    = lane >> 4;     // k quad

    // Bijective XCD swizzle (1536 % 8 == 0): each XCD gets 192 consecutive
    // tiles = 4 full M-panels (4 x 1MB A fits its 4MB L2).
    const int bid = blockIdx.x;
    const int swz = (bid & 7) * CPX + (bid >> 3);
    const int tn  = swz % (N_OUT / BN);
    const int tm  = swz / (N_OUT / BN);
    const int m0  = tm * BM;
    const int n0  = tn * BN;

    // ---- staging addressing (constant per thread) ----
    const int f0   = tid * 16;                 // flat byte in 16 KiB half-tile
    const int r0   = tid >> 3;                 // row 0..63 (load 1 adds 64)
    const int swzK = (((tid & 7) ^ ((tid >> 3) & 7)) << 4);  // source k-block swizzle
    const int8_t* gA = Aq + (size_t)(m0 + r0) * K_IN + swzK;
    const int8_t* gB = Bq + (size_t)(n0 + r0) * K_IN + swzK;

    auto stageA = [&](int t, int half, int dbuf) {
        const int8_t* src = gA + (size_t)half * (128 * K_IN) + t * BK;
        int8_t* dst = sm + dbuf * 32768 + half * 16384 + f0;
        __builtin_amdgcn_global_load_lds(
            (const __attribute__((address_space(1))) void*)src,
            (__attribute__((address_space(3))) void*)dst, 16, 0, 0);
        __builtin_amdgcn_global_load_lds(
            (const __attribute__((address_space(1))) void*)(src + (size_t)64 * K_IN),
            (__attribute__((address_space(3))) void*)(dst + 8192), 16, 0, 0);
    };
    auto stageB = [&](int t, int half, int dbuf) {
        const int8_t* src = gB + (size_t)half * (128 * K_IN) + t * BK;
        int8_t* dst = sm + 65536 + dbuf * 32768 + half * 16384 + f0;
        __builtin_amdgcn_global_load_lds(
            (const __attribute__((address_space(1))) void*)src,
            (__attribute__((address_space(3))) void*)dst, 16, 0, 0);
        __builtin_amdgcn_global_load_lds(
            (const __attribute__((address_space(1))) void*)(src + (size_t)64 * K_IN),
            (__attribute__((address_space(3))) void*)(dst + 8192), 16, 0, 0);
    };

    // ---- fragment read addressing ----
    const int aOff = wm * 16384 + fr * 128;    // within A buffer
    const int bOff = wn * 8192  + fr * 128;    // within B buffer
    const int kb0  = ((0 + q) ^ (fr & 7)) << 4;  // kk=0 k-block (swizzled)
    const int kb1  = ((4 + q) ^ (fr & 7)) << 4;  // kk=1

    int32x4 acc[8][4] = {};

    // ---- prologue: tile0 complete + first 2 half-tiles of tile1 ----
    stageB(0, 0, 0); stageA(0, 0, 0); stageB(0, 1, 0); stageA(0, 1, 0);
    stageB(1, 0, 1); stageA(1, 0, 1);
    asm volatile("s_waitcnt vmcnt(4)" ::: "memory");  // tile0 landed
    BAR();

    for (int j = 0; j < NT; ++j) {
        const int buf = j & 1;
        const int8_t* As = sm + buf * 32768;
        const int8_t* Bs = sm + 65536 + buf * 32768;
        int32x4 a[4][2], b[4][2];

        // -------- P0: read A-lo + B-lo; stage B-half1(j+1) --------
#pragma unroll
        for (int im = 0; im < 4; ++im) {
            a[im][0] = *(const int32x4*)(As + aOff + im * 2048 + kb0);
            a[im][1] = *(const int32x4*)(As + aOff + im * 2048 + kb1);
        }
#pragma unroll
        for (int in = 0; in < 2; ++in) {
            b[in][0] = *(const int32x4*)(Bs + bOff + in * 2048 + kb0);
            b[in][1] = *(const int32x4*)(Bs + bOff + in * 2048 + kb1);
        }
        if (j + 1 < NT) stageB(j + 1, 1, buf ^ 1);
        asm volatile("s_waitcnt lgkmcnt(8)" ::: "memory");
        BAR();
        LGKM0();
        __builtin_amdgcn_s_setprio(1);
        mfma_quad<0, 0>(acc, a, b);
        __builtin_amdgcn_s_setprio(0);
        BAR();

        // -------- P1: read B-hi; stage A-half1(j+1) --------
#pragma unroll
        for (int in = 0; in < 2; ++in) {
            b[2 + in][0] = *(const int32x4*)(Bs + bOff + (2 + in) * 2048 + kb0);
            b[2 + in][1] = *(const int32x4*)(Bs + bOff + (2 + in) * 2048 + kb1);
        }
        if (j + 1 < NT) stageA(j + 1, 1, buf ^ 1);
        BAR();
        LGKM0();
        __builtin_amdgcn_s_setprio(1);
        mfma_quad<0, 2>(acc, a, b);
        __builtin_amdgcn_s_setprio(0);
        BAR();

        // -------- P2: read A-hi; stage B-half0(j+2) (B halves free after P1) --------
#pragma unroll
        for (int im = 0; im < 4; ++im) {
            a[im][0] = *(const int32x4*)(As + aOff + 8192 + im * 2048 + kb0);
            a[im][1] = *(const int32x4*)(As + aOff + 8192 + im * 2048 + kb1);
        }
        if (j + 2 < NT) stageB(j + 2, 0, buf);
        BAR();
        LGKM0();
        __builtin_amdgcn_s_setprio(1);
        mfma_quad<4, 2>(acc, a, b);
        __builtin_amdgcn_s_setprio(0);
        BAR();

        // -------- P3: stage A-half0(j+2) (A halves free after P2); boundary vmcnt --------
        if (j + 2 < NT) stageA(j + 2, 0, buf);
        BAR();
        __builtin_amdgcn_s_setprio(1);
        mfma_quad<4, 0>(acc, a, b);   // B-lo regs still live from P0
        __builtin_amdgcn_s_setprio(0);
        if (j < NT - 2)
            asm volatile("s_waitcnt vmcnt(4)" ::: "memory");  // tile j+1 fully landed
        else if (j == NT - 2)
            asm volatile("s_waitcnt vmcnt(0)" ::: "memory");  // drain for last tile
        BAR();
    }

    // ---- epilogue: C/D layout col=lane&15, row=q*4+reg (verified) ----
    float wv[4], bv[4];
#pragma unroll
    for (int in = 0; in < 4; ++in) {
        const int n = n0 + wn * 64 + in * 16 + fr;
        wv[in] = wsc[n];
        bv[in] = bias[n];
    }
#pragma unroll
    for (int im = 0; im < 8; ++im) {
#pragma unroll
        for (int i = 0; i < 4; ++i) {
            const int m = m0 + wm * 128 + im * 16 + q * 4 + i;
            const float sa = xs[m];
            float* orow = out + (size_t)m * N_OUT + n0 + wn * 64;
#pragma unroll
            for (int in = 0; in < 4; ++in)
                orow[in * 16 + fr] = (float)acc[im][in][i] * sa * wv[in] + bv[in];
        }
    }
}

extern "C" void kernel_launch(void* const* d_in, const int* in_sizes, int n_in,
                              void* d_out, int out_size, void* d_ws, size_t ws_size,
                              hipStream_t stream) {
    const float* x    = (const float*)d_in[0];
    const int*   wgt  = (const int*)d_in[1];     // int8 values widened to int32
    const float* wsc  = (const float*)d_in[2];   // [N_OUT]
    const float* bias = (const float*)d_in[3];   // [N_OUT]
    float* out = (float*)d_out;

    uint8_t* ws = (uint8_t*)d_ws;
    float*  xs = (float*)ws;                                        // 32 KB
    int8_t* xq = (int8_t*)(ws + 32768);                             // 33.55 MB
    int8_t* wq = (int8_t*)(ws + 32768 + (size_t)T_TOKENS * K_IN);   // 50.33 MB

    static bool inited = false;
    if (!inited) {
        hipFuncSetAttribute((const void*)gemm_i8,
                            hipFuncAttributeMaxDynamicSharedMemorySize, 131072);
        inited = true;
    }

    hipLaunchKernelGGL(pack_weight,
                       dim3(((size_t)N_OUT * K_IN) / 4 / 256), dim3(256), 0, stream,
                       wgt, wq);
    hipLaunchKernelGGL(quant_rows, dim3(T_TOKENS), dim3(256), 0, stream, x, xq, xs);
    hipLaunchKernelGGL(gemm_i8, dim3(GRID_X), dim3(512), 131072, stream,
                       xq, wq, xs, wsc, bias, out);
}